// Round 11
// baseline (110.218 us; speedup 1.0000x reference)
//
#include <hip/hip_runtime.h>
#include <math.h>

#define NN 512
#define FF 64
#define HH 4

// ---------------- ws layout (floats) ----------------
// dinv : [512]               off 0
// cvec : [512]               off 512
// T    : [B*H*N]   = 8192    off 1024
// q_t  : [B*H*N*F] = 2097152 off 9216
// kT   : [B*H*16][N][4] = 2097152 off 2106368   (feature-interleaved float4)

// S1: q/k projection (1024 blocks x 256 thr, 4-row tiles, q XOR k per block)
//     + side jobs: dinv rows (blocks 0-511, wave 0), zero T (blocks 0-127,
//     wave 1), zero cvec (blocks 0-7, wave 2).
//     k written to interleaved kT[bh][f/4][j][f%4] (16B-segment stores).
__global__ __launch_bounds__(256) void k_s1(const float* __restrict__ x,
                                            const float* __restrict__ Wq,
                                            const float* __restrict__ bq,
                                            const float* __restrict__ Wk,
                                            const float* __restrict__ bk,
                                            const float* __restrict__ adj,
                                            float* __restrict__ q_t,
                                            float* __restrict__ kT,
                                            float* __restrict__ dinv,
                                            float* __restrict__ T,
                                            float* __restrict__ cvec) {
    __shared__ float x_lds[4][64];
    int blk = blockIdx.x, tid = threadIdx.x;
    int wave = tid >> 6, lane = tid & 63;

    if (blk < 512 && wave == 0) {
        float acc = 0.f;
#pragma unroll
        for (int k = 0; k < 8; ++k) acc += adj[(long)blk * NN + k * 64 + lane];
        for (int o = 32; o > 0; o >>= 1) acc += __shfl_xor(acc, o);
        if (lane == 0) dinv[blk] = 1.0f / sqrtf(acc + 1.0f);
    }
    if (blk < 128 && wave == 1) T[blk * 64 + lane] = 0.f;
    if (blk < 8 && wave == 2) cvec[blk * 64 + lane] = 0.f;

    int b = blk >> 8, rest = blk & 255, isK = rest >> 7, itile = rest & 127;
    int i0 = itile * 4;
    x_lds[tid >> 6][tid & 63] = x[((long)b * NN + i0 + (tid >> 6)) * FF + (tid & 63)];
    __syncthreads();
    const float* W = isK ? Wk : Wq;
    float bv = (isK ? bk : bq)[tid];
    float a0 = bv, a1 = bv, a2 = bv, a3 = bv;
    for (int cc = 0; cc < 64; ++cc) {
        float w = W[cc * 256 + tid];
        a0 = fmaf(x_lds[0][cc], w, a0);
        a1 = fmaf(x_lds[1][cc], w, a1);
        a2 = fmaf(x_lds[2][cc], w, a2);
        a3 = fmaf(x_lds[3][cc], w, a3);
    }
    int h = tid >> 6, f = tid & 63;
    int bh = b * HH + h;
    if (!isK) {
        long base = ((long)bh * NN + i0) * FF + f;
        q_t[base] = a0; q_t[base + FF] = a1;
        q_t[base + 2 * FF] = a2; q_t[base + 3 * FF] = a3;
    } else {
        // kT[bh][f>>2][j][f&3]
        float* kp = kT + (((long)(bh * 16 + (f >> 2)) * NN + i0) << 2) + (f & 3);
        kp[0] = a0; kp[4] = a1; kp[8] = a2; kp[12] = a3;
    }
}

// S2: scores -> softmax -> noradj weighting -> atomicAdd into T (+cvec).
//     1024 blocks x 256 thr, 8 i-rows each, 2 j per thread.
//     kT loads: one float4 per 4 features (32 b128 loads/thread, lanes
//     contiguous -> 1KB/instr coalescing).
__global__ __launch_bounds__(256) void k_s2(const float* __restrict__ q_t,
                                            const float* __restrict__ kT,
                                            const float* __restrict__ adj,
                                            const float* __restrict__ dinv,
                                            float* __restrict__ T,
                                            float* __restrict__ cvec) {
    __shared__ float q_lds[8][64];
    __shared__ float red[8][4];
    __shared__ float red2[8][4];
    int blk = blockIdx.x, tid = threadIdx.x;
    int itile = blk & 63, h = (blk >> 6) & 3, b = blk >> 8;
    int bh = b * HH + h, i0 = itile * 8;
    int wv = tid >> 6, lane = tid & 63;
#pragma unroll
    for (int k = 0; k < 2; ++k) {
        int idx = k * 256 + tid;
        q_lds[idx >> 6][idx & 63] =
            q_t[((long)bh * NN + i0 + (idx >> 6)) * FF + (idx & 63)];
    }
    __syncthreads();
    int j0 = tid, j1 = tid + 256;
    const float4* kb4 = (const float4*)kT + (long)bh * 16 * NN;
    float s0[8], s1[8];
#pragma unroll
    for (int r = 0; r < 8; ++r) { s0[r] = 0.f; s1[r] = 0.f; }
#pragma unroll 4
    for (int g = 0; g < 16; ++g) {
        float4 kv0 = kb4[g * NN + j0];
        float4 kv1 = kb4[g * NN + j1];
#pragma unroll
        for (int r = 0; r < 8; ++r) {
            float4 qv = *(const float4*)&q_lds[r][g * 4];
            s0[r] = fmaf(qv.x, kv0.x, s0[r]);
            s0[r] = fmaf(qv.y, kv0.y, s0[r]);
            s0[r] = fmaf(qv.z, kv0.z, s0[r]);
            s0[r] = fmaf(qv.w, kv0.w, s0[r]);
            s1[r] = fmaf(qv.x, kv1.x, s1[r]);
            s1[r] = fmaf(qv.y, kv1.y, s1[r]);
            s1[r] = fmaf(qv.z, kv1.z, s1[r]);
            s1[r] = fmaf(qv.w, kv1.w, s1[r]);
        }
    }
    const float scale = 0.125f;   // 1/sqrt(64)
    float m[8];
#pragma unroll
    for (int r = 0; r < 8; ++r) {
        float v = fmaxf(s0[r], s1[r]);
        for (int o = 32; o > 0; o >>= 1) v = fmaxf(v, __shfl_xor(v, o));
        if (lane == 0) red[r][wv] = v;
    }
    __syncthreads();
#pragma unroll
    for (int r = 0; r < 8; ++r)
        m[r] = fmaxf(fmaxf(red[r][0], red[r][1]), fmaxf(red[r][2], red[r][3]));
#pragma unroll
    for (int r = 0; r < 8; ++r) {
        s0[r] = __expf((s0[r] - m[r]) * scale);
        s1[r] = __expf((s1[r] - m[r]) * scale);
        float v = s0[r] + s1[r];
        for (int o = 32; o > 0; o >>= 1) v += __shfl_xor(v, o);
        if (lane == 0) red2[r][wv] = v;
    }
    __syncthreads();
    float dj0 = dinv[j0], dj1 = dinv[j1];
    float pw0 = 0.f, pw1 = 0.f, cw0 = 0.f, cw1 = 0.f;
#pragma unroll
    for (int r = 0; r < 8; ++r) {
        float Zi = 1.0f / (red2[r][0] + red2[r][1] + red2[r][2] + red2[r][3]);
        int gi = i0 + r;
        float di = dinv[gi];
        float a0 = adj[(long)gi * NN + j0] + (gi == j0 ? 1.f : 0.f);
        float a1 = adj[(long)gi * NN + j1] + (gi == j1 ? 1.f : 0.f);
        float t0 = di * a0, t1 = di * a1;
        pw0 = fmaf(t0, s0[r] * Zi, pw0);
        pw1 = fmaf(t1, s1[r] * Zi, pw1);
        cw0 += t0;
        cw1 += t1;
    }
    atomicAdd(&T[bh * NN + j0], pw0 * dj0);
    atomicAdd(&T[bh * NN + j1], pw1 * dj1);
    if (b == 0 && h == 0) {
        atomicAdd(&cvec[j0], cw0);
        atomicAdd(&cvec[j1], cw1);
    }
}

// S3: fused sxd + SpMM + FC + relu. 1024 blocks x 256 thr, 2 rows each,
//     4-way j-split, LDS staging of per-j scalars.  [R4/R10-measured best]
__global__ __launch_bounds__(256) void k_s3(const float* __restrict__ x,
                                            const float* __restrict__ T,
                                            const float* __restrict__ Wlin,
                                            const float* __restrict__ blin,
                                            const float* __restrict__ cvec,
                                            const float* __restrict__ adj,
                                            const float* __restrict__ dinv,
                                            const float* __restrict__ Wfc,
                                            const float* __restrict__ bfc,
                                            float* __restrict__ out) {
    __shared__ float4 u4_l[NN];      // dj*T[h][j], h=0..3
    __shared__ float  u0_l[NN];      // dj*dj*cvec[j]
    __shared__ float2 ad_l[NN];      // A[i0,j], A[i0+1,j] (identity folded)
    __shared__ float part[4][2][64];
    __shared__ float m_lds[2][64];
    __shared__ float part2[4][2][64];
    int blk = blockIdx.x, tid = threadIdx.x;
    int b = blk >> 8, itile = blk & 255;
    int i0 = itile * 2;

    for (int jj = tid; jj < NN; jj += 256) {
        float dj = dinv[jj];
        u0_l[jj] = dj * dj * cvec[jj];
        u4_l[jj] = make_float4(dj * T[(b * HH + 0) * NN + jj],
                               dj * T[(b * HH + 1) * NN + jj],
                               dj * T[(b * HH + 2) * NN + jj],
                               dj * T[(b * HH + 3) * NN + jj]);
        ad_l[jj] = make_float2(adj[(long)i0 * NN + jj] + (i0 == jj ? 1.f : 0.f),
                               adj[(long)(i0 + 1) * NN + jj] + (i0 + 1 == jj ? 1.f : 0.f));
    }
    __syncthreads();

    int f = tid & 63, jc = tid >> 6;
    int jb = jc * 128;
    float blf = blin[f];
    float4 wl = make_float4(Wlin[f], Wlin[64 + f], Wlin[128 + f], Wlin[192 + f]);
    const float* xb = x + (long)b * NN * FF + f;
    float a0 = 0.f, a1 = 0.f;
#pragma unroll 4
    for (int j = jb; j < jb + 128; ++j) {
        float xv = xb[(long)j * FF];
        float4 u = u4_l[j];
        float2 ad = ad_l[j];
        float S = blf * u0_l[j];
        S = fmaf(wl.x, u.x, S);
        S = fmaf(wl.y, u.y, S);
        S = fmaf(wl.z, u.z, S);
        S = fmaf(wl.w, u.w, S);
        float sx = xv * S;
        a0 = fmaf(ad.x, sx, a0);
        a1 = fmaf(ad.y, sx, a1);
    }
    part[jc][0][f] = a0;
    part[jc][1][f] = a1;
    __syncthreads();
    if (jc == 0) {
        m_lds[0][f] = (part[0][0][f] + part[1][0][f] + part[2][0][f] + part[3][0][f]) * dinv[i0];
        m_lds[1][f] = (part[0][1][f] + part[1][1][f] + part[2][1][f] + part[3][1][f]) * dinv[i0 + 1];
    }
    __syncthreads();
    float o0 = 0.f, o1 = 0.f;
    int c0 = jc * 16;
#pragma unroll
    for (int cc = 0; cc < 16; ++cc) {
        float w = Wfc[(c0 + cc) * FF + f];
        o0 = fmaf(m_lds[0][c0 + cc], w, o0);
        o1 = fmaf(m_lds[1][c0 + cc], w, o1);
    }
    part2[jc][0][f] = o0;
    part2[jc][1][f] = o1;
    __syncthreads();
    if (jc == 0) {
        float bb = bfc[f];
        float r0 = part2[0][0][f] + part2[1][0][f] + part2[2][0][f] + part2[3][0][f] + bb;
        float r1 = part2[0][1][f] + part2[1][1][f] + part2[2][1][f] + part2[3][1][f] + bb;
        out[((long)b * NN + i0) * FF + f]     = fmaxf(r0, 0.f);
        out[((long)b * NN + i0 + 1) * FF + f] = fmaxf(r1, 0.f);
    }
}

extern "C" void kernel_launch(void* const* d_in, const int* in_sizes, int n_in,
                              void* d_out, int out_size, void* d_ws, size_t ws_size,
                              hipStream_t stream) {
    const float* x    = (const float*)d_in[0];
    const float* adj  = (const float*)d_in[1];
    const float* Wq   = (const float*)d_in[2];
    const float* bq   = (const float*)d_in[3];
    const float* Wk   = (const float*)d_in[4];
    const float* bk   = (const float*)d_in[5];
    const float* Wlin = (const float*)d_in[6];
    const float* blin = (const float*)d_in[7];
    const float* Wfc  = (const float*)d_in[8];
    const float* bfc  = (const float*)d_in[9];
    float* out = (float*)d_out;

    float* ws   = (float*)d_ws;
    float* dinv = ws;                 // 512
    float* cvec = ws + 512;           // 512
    float* T    = ws + 1024;          // 8192
    float* q_t  = ws + 9216;          // 2097152
    float* kT   = ws + 2106368;       // 2097152

    k_s1<<<dim3(1024), dim3(256), 0, stream>>>(x, Wq, bq, Wk, bk, adj, q_t, kT, dinv, T, cvec);
    k_s2<<<dim3(1024), dim3(256), 0, stream>>>(q_t, kT, adj, dinv, T, cvec);
    k_s3<<<dim3(1024), dim3(256), 0, stream>>>(x, T, Wlin, blin, cvec, adj, dinv, Wfc, bfc, out);
}